// Round 3
// baseline (584.823 us; speedup 1.0000x reference)
//
#include <hip/hip_runtime.h>
#include <hip/hip_bf16.h>
#include <cmath>
#include <type_traits>

#define DIMC 2048
#define NHEADS 16
#define HDIM 128
#define SEQT 2048
#define BATCH 2

using frag8 = __attribute__((ext_vector_type(8))) short;   // 8 bf16 = 4 VGPRs
using f32x4 = __attribute__((ext_vector_type(4))) float;

#define MFMA(a, b, c) __builtin_amdgcn_mfma_f32_16x16x32_bf16((a), (b), (c), 0, 0, 0)

#define GLOAD_LDS(g, l)                                              \
  __builtin_amdgcn_global_load_lds(                                  \
      (const __attribute__((address_space(1))) void*)(g),            \
      (__attribute__((address_space(3))) void*)(l), 16, 0, 0)

// ---------------- fallback: zero the output (ws too small -> visible failure, not a fault) ----
__global__ void zero_out_kernel(float* __restrict__ out, int n) {
  int i = blockIdx.x * blockDim.x + threadIdx.x;
  if (i < n) out[i] = 0.0f;
}

// ---------------- cast f32 -> bf16 (float4 vectorized) ----------------
__global__ void cast_f32_bf16(const float* __restrict__ in,
                              __hip_bfloat16* __restrict__ out, int n4) {
  int i = blockIdx.x * blockDim.x + threadIdx.x;
  if (i >= n4) return;
  float4 v = reinterpret_cast<const float4*>(in)[i];
  union { __hip_bfloat16 h[4]; ushort4 u; } cv;
  cv.h[0] = __float2bfloat16(v.x);
  cv.h[1] = __float2bfloat16(v.y);
  cv.h[2] = __float2bfloat16(v.z);
  cv.h[3] = __float2bfloat16(v.w);
  reinterpret_cast<ushort4*>(out)[i] = cv.u;
}

// ---------------- RoPE cos/sin table: [T][64] float2 ----------------
__global__ void rope_tab_kernel(float* __restrict__ tab) {
  int idx = blockIdx.x * blockDim.x + threadIdx.x;
  if (idx >= SEQT * 64) return;
  int j = idx & 63, t = idx >> 6;
  float inv = expf(-9.210340371976184f * (float)j / 64.0f);  // 10000^(-j/64)
  float ang = (float)t * inv;
  tab[idx * 2] = cosf(ang);
  tab[idx * 2 + 1] = sinf(ang);
}

// ---------------- m97-style bf16 GEMM:  C[M,N] = A[M,K] * B[N,K]^T ----------------
// 128x128 tile, BK=32, 256 thr (4 waves, 2x2 of 64x64), global_load_lds width 16
template <typename CT>
__global__ __launch_bounds__(256) void gemm_bt(
    const __hip_bfloat16* __restrict__ A, const __hip_bfloat16* __restrict__ Bm,
    CT* __restrict__ C, int M, int N, int K) {
  __shared__ __hip_bfloat16 As[128 * 32];
  __shared__ __hip_bfloat16 Bs[128 * 32];
  const int tid = threadIdx.x;
  const int lane = tid & 63;
  const int wave = tid >> 6;
  const int wr = wave >> 1, wc = wave & 1;
  const int m0 = blockIdx.y * 128, n0 = blockIdx.x * 128;
  const int lr = lane & 15, lg = lane >> 4;

  const __hip_bfloat16* Ap = A + (size_t)(m0 + (tid >> 2)) * K + (tid & 3) * 8;
  const __hip_bfloat16* Bp = Bm + (size_t)(n0 + (tid >> 2)) * K + (tid & 3) * 8;
  __hip_bfloat16* Asd = As + tid * 8;
  __hip_bfloat16* Bsd = Bs + tid * 8;

  f32x4 acc[4][4] = {};

  for (int k0 = 0; k0 < K; k0 += 32) {
    GLOAD_LDS(Ap + k0, Asd);
    GLOAD_LDS(Ap + (size_t)64 * K + k0, Asd + 2048);
    GLOAD_LDS(Bp + k0, Bsd);
    GLOAD_LDS(Bp + (size_t)64 * K + k0, Bsd + 2048);
    __syncthreads();
    frag8 a[4], b[4];
#pragma unroll
    for (int mi = 0; mi < 4; ++mi)
      a[mi] = *reinterpret_cast<const frag8*>(&As[(wr * 64 + mi * 16 + lr) * 32 + lg * 8]);
#pragma unroll
    for (int nj = 0; nj < 4; ++nj)
      b[nj] = *reinterpret_cast<const frag8*>(&Bs[(wc * 64 + nj * 16 + lr) * 32 + lg * 8]);
#pragma unroll
    for (int mi = 0; mi < 4; ++mi)
#pragma unroll
      for (int nj = 0; nj < 4; ++nj)
        acc[mi][nj] = MFMA(a[mi], b[nj], acc[mi][nj]);
    __syncthreads();
  }

#pragma unroll
  for (int mi = 0; mi < 4; ++mi)
#pragma unroll
    for (int nj = 0; nj < 4; ++nj)
#pragma unroll
      for (int i = 0; i < 4; ++i) {
        int row = m0 + wr * 64 + mi * 16 + lg * 4 + i;
        int col = n0 + wc * 64 + nj * 16 + lr;
        float v = acc[mi][nj][i];
        if constexpr (std::is_same<CT, __hip_bfloat16>::value)
          C[(size_t)row * N + col] = __float2bfloat16(v);
        else
          C[(size_t)row * N + col] = v;
      }
}

// ---------------- RoPE on q,k; scatter to [B,H,T,D]; fold 1/sqrt(128) into q ----------------
__global__ void rope_qk(const __hip_bfloat16* __restrict__ qkv,
                        const float* __restrict__ tab,
                        __hip_bfloat16* __restrict__ q,
                        __hip_bfloat16* __restrict__ k) {
  int idx = blockIdx.x * blockDim.x + threadIdx.x;  // B*T*H*64
  if (idx >= BATCH * SEQT * NHEADS * 64) return;
  int j = idx & 63;
  int h = (idx >> 6) & 15;
  int t = (idx >> 10) & 2047;
  int b = idx >> 21;
  float c = tab[(t * 64 + j) * 2];
  float s = tab[(t * 64 + j) * 2 + 1];
  size_t qi = (size_t)(b * SEQT + t) * (3 * DIMC) + h * HDIM + j;
  float q1 = __bfloat162float(qkv[qi]);
  float q2 = __bfloat162float(qkv[qi + 64]);
  float k1 = __bfloat162float(qkv[qi + DIMC]);
  float k2 = __bfloat162float(qkv[qi + DIMC + 64]);
  const float sc = 0.08838834764831845f;  // 1/sqrt(128)
  size_t oi = ((size_t)(b * NHEADS + h) * SEQT + t) * HDIM + j;
  q[oi] = __float2bfloat16((q1 * c - q2 * s) * sc);
  q[oi + 64] = __float2bfloat16((q1 * s + q2 * c) * sc);
  k[oi] = __float2bfloat16(k1 * c - k2 * s);
  k[oi + 64] = __float2bfloat16(k1 * s + k2 * c);
}

// ---------------- V transpose: qkv v-part -> vt[B,H,D,T] ----------------
__global__ __launch_bounds__(256) void transpose_v(
    const __hip_bfloat16* __restrict__ qkv, __hip_bfloat16* __restrict__ vt) {
  __shared__ __hip_bfloat16 tile[32][33];
  int t0 = blockIdx.x * 32;
  int d0 = blockIdx.y * 32;
  int bh = blockIdx.z;
  int b = bh >> 4, h = bh & 15;
  int x = threadIdx.x & 31, y = threadIdx.x >> 5;  // y: 0..7
#pragma unroll
  for (int r = 0; r < 4; ++r) {
    int tr = r * 8 + y;
    tile[tr][x] = qkv[(size_t)(b * SEQT + t0 + tr) * (3 * DIMC) + 2 * DIMC + h * HDIM + d0 + x];
  }
  __syncthreads();
#pragma unroll
  for (int r = 0; r < 4; ++r) {
    int dr = r * 8 + y;
    vt[((size_t)bh * HDIM + d0 + dr) * SEQT + t0 + x] = tile[x][dr];
  }
}

// ---------------- flash attention: 1 wave per 32 q-rows, KB=32 ----------------
__global__ __launch_bounds__(64) void flash_attn(
    const __hip_bfloat16* __restrict__ q, const __hip_bfloat16* __restrict__ k,
    const __hip_bfloat16* __restrict__ vt, __hip_bfloat16* __restrict__ ctx) {
  const int qt = blockIdx.x & 63;   // q-tile (32 rows)
  const int bh = blockIdx.x >> 6;   // b*16+h
  const int lane = threadIdx.x;
  const int lr = lane & 15, lg = lane >> 4;
  const size_t base = (size_t)bh * SEQT * HDIM;

  __shared__ __hip_bfloat16 P[32 * 40];  // stride 40 elems (80B = 5*16B): aligned b128 reads

  frag8 aq[2][4];
#pragma unroll
  for (int rt = 0; rt < 2; ++rt)
#pragma unroll
    for (int dc = 0; dc < 4; ++dc)
      aq[rt][dc] = *reinterpret_cast<const frag8*>(
          &q[base + (size_t)(qt * 32 + rt * 16 + lr) * HDIM + dc * 32 + lg * 8]);

  f32x4 o[2][8] = {};
  float mrun[2][4], lrun[2][4];
#pragma unroll
  for (int rt = 0; rt < 2; ++rt)
#pragma unroll
    for (int i = 0; i < 4; ++i) { mrun[rt][i] = -INFINITY; lrun[rt][i] = 0.f; }

  for (int kb = 0; kb <= qt; ++kb) {
    frag8 bk[2][4];
#pragma unroll
    for (int st = 0; st < 2; ++st)
#pragma unroll
      for (int dc = 0; dc < 4; ++dc)
        bk[st][dc] = *reinterpret_cast<const frag8*>(
            &k[base + (size_t)(kb * 32 + st * 16 + lr) * HDIM + dc * 32 + lg * 8]);

    f32x4 s[2][2] = {};
#pragma unroll
    for (int rt = 0; rt < 2; ++rt)
#pragma unroll
      for (int st = 0; st < 2; ++st)
#pragma unroll
        for (int dc = 0; dc < 4; ++dc)
          s[rt][st] = MFMA(aq[rt][dc], bk[st][dc], s[rt][st]);

    if (kb == qt) {  // diagonal block: causal mask (local coords)
#pragma unroll
      for (int rt = 0; rt < 2; ++rt)
#pragma unroll
        for (int st = 0; st < 2; ++st)
#pragma unroll
          for (int i = 0; i < 4; ++i)
            if (st * 16 + lr > rt * 16 + lg * 4 + i) s[rt][st][i] = -INFINITY;
    }

#pragma unroll
    for (int rt = 0; rt < 2; ++rt)
#pragma unroll
      for (int i = 0; i < 4; ++i) {
        float pm = fmaxf(s[rt][0][i], s[rt][1][i]);
        pm = fmaxf(pm, __shfl_xor(pm, 1, 16));
        pm = fmaxf(pm, __shfl_xor(pm, 2, 16));
        pm = fmaxf(pm, __shfl_xor(pm, 4, 16));
        pm = fmaxf(pm, __shfl_xor(pm, 8, 16));
        float mn = fmaxf(mrun[rt][i], pm);
        float sf = __expf(mrun[rt][i] - mn);
        mrun[rt][i] = mn;
        float p0 = __expf(s[rt][0][i] - mn);
        float p1 = __expf(s[rt][1][i] - mn);
        float rs = p0 + p1;
        rs += __shfl_xor(rs, 1, 16);
        rs += __shfl_xor(rs, 2, 16);
        rs += __shfl_xor(rs, 4, 16);
        rs += __shfl_xor(rs, 8, 16);
        lrun[rt][i] = lrun[rt][i] * sf + rs;
#pragma unroll
        for (int dt = 0; dt < 8; ++dt) o[rt][dt][i] *= sf;
        P[(rt * 16 + lg * 4 + i) * 40 + lr] = __float2bfloat16(p0);
        P[(rt * 16 + lg * 4 + i) * 40 + 16 + lr] = __float2bfloat16(p1);
      }
    __syncthreads();

    frag8 pa[2];
#pragma unroll
    for (int rt = 0; rt < 2; ++rt)
      pa[rt] = *reinterpret_cast<const frag8*>(&P[(rt * 16 + lr) * 40 + lg * 8]);

    frag8 bv[8];
#pragma unroll
    for (int dt = 0; dt < 8; ++dt)
      bv[dt] = *reinterpret_cast<const frag8*>(
          &vt[base + (size_t)(dt * 16 + lr) * SEQT + kb * 32 + lg * 8]);
#pragma unroll
    for (int rt = 0; rt < 2; ++rt)
#pragma unroll
      for (int dt = 0; dt < 8; ++dt)
        o[rt][dt] = MFMA(pa[rt], bv[dt], o[rt][dt]);
    __syncthreads();
  }

  const int b = bh >> 4, h = bh & 15;
#pragma unroll
  for (int rt = 0; rt < 2; ++rt)
#pragma unroll
    for (int i = 0; i < 4; ++i) {
      float inv = 1.0f / lrun[rt][i];
      int row = qt * 32 + rt * 16 + lg * 4 + i;
#pragma unroll
      for (int dt = 0; dt < 8; ++dt)
        ctx[(size_t)(b * SEQT + row) * DIMC + h * HDIM + dt * 16 + lr] =
            __float2bfloat16(o[rt][dt][i] * inv);
    }
}

// ---------------- launch ----------------
extern "C" void kernel_launch(void* const* d_in, const int* in_sizes, int n_in,
                              void* d_out, int out_size, void* d_ws, size_t ws_size,
                              hipStream_t stream) {
  const float* x = (const float*)d_in[0];
  const float* w_qkv = (const float*)d_in[1];
  const float* w_out = (const float*)d_in[2];
  float* out = (float*)d_out;
  char* ws = (char*)d_ws;

  // ws layout (stream-ordered aliasing; total 110,100,480 B):
  //  [0, 50.3M)       qkvb ; ctx aliases [0, 16.8M) after qkvb is dead
  //  [48M, 64M)       qbuf (aliases xb, xb dead after gemm_qkv)
  //  [64M, 80M)       kbuf \ wqkvb spans [64M, 88M), dead after gemm_qkv
  //  [80M, 96M)       vtb  /
  //  [96M, 104M)      woutb ; [104M, 105M) rope table
  const size_t WS_NEEDED = 110100480;
  if (ws_size < WS_NEEDED) {  // defensive: visible wrong-output instead of an OOB fault
    zero_out_kernel<<<(out_size + 255) / 256, 256, 0, stream>>>(out, out_size);
    return;
  }

  __hip_bfloat16* qkvb  = (__hip_bfloat16*)(ws);
  __hip_bfloat16* ctx   = (__hip_bfloat16*)(ws);
  __hip_bfloat16* qbuf  = (__hip_bfloat16*)(ws + 50331648);
  __hip_bfloat16* kbuf  = (__hip_bfloat16*)(ws + 67108864);
  __hip_bfloat16* vtb   = (__hip_bfloat16*)(ws + 83886080);
  __hip_bfloat16* xb    = (__hip_bfloat16*)(ws + 50331648);
  __hip_bfloat16* wqkvb = (__hip_bfloat16*)(ws + 67108864);
  __hip_bfloat16* woutb = (__hip_bfloat16*)(ws + 100663296);
  float* tab            = (float*)(ws + 109051904);

  cast_f32_bf16<<<8192, 256, 0, stream>>>(x, xb, 2097152);
  cast_f32_bf16<<<12288, 256, 0, stream>>>(w_qkv, wqkvb, 3145728);
  cast_f32_bf16<<<4096, 256, 0, stream>>>(w_out, woutb, 1048576);
  rope_tab_kernel<<<512, 256, 0, stream>>>(tab);
  gemm_bt<__hip_bfloat16><<<dim3(48, 32), 256, 0, stream>>>(xb, wqkvb, qkvb, 4096, 6144, 2048);
  rope_qk<<<16384, 256, 0, stream>>>(qkvb, tab, qbuf, kbuf);
  transpose_v<<<dim3(64, 4, 32), 256, 0, stream>>>(qkvb, vtb);
  flash_attn<<<2048, 64, 0, stream>>>(qbuf, kbuf, vtb, ctx);
  gemm_bt<float><<<dim3(16, 32), 256, 0, stream>>>(ctx, woutb, out, 4096, 2048, 2048);
}

// Round 5
// 529.667 us; speedup vs baseline: 1.1041x; 1.1041x over previous
//
#include <hip/hip_runtime.h>
#include <hip/hip_bf16.h>
#include <cmath>
#include <type_traits>

#define DIMC 2048
#define NHEADS 16
#define HDIM 128
#define SEQT 2048
#define BATCH 2

using frag8 = __attribute__((ext_vector_type(8))) short;   // 8 bf16 = 4 VGPRs
using f32x4 = __attribute__((ext_vector_type(4))) float;

#define MFMA(a, b, c) __builtin_amdgcn_mfma_f32_16x16x32_bf16((a), (b), (c), 0, 0, 0)

#define GLOAD_LDS(g, l)                                              \
  __builtin_amdgcn_global_load_lds(                                  \
      (const __attribute__((address_space(1))) void*)(g),            \
      (__attribute__((address_space(3))) void*)(l), 16, 0, 0)

// ---------------- fallback: zero the output (ws too small -> visible failure, not a fault) ----
__global__ void zero_out_kernel(float* __restrict__ out, int n) {
  int i = blockIdx.x * blockDim.x + threadIdx.x;
  if (i < n) out[i] = 0.0f;
}

// ---------------- cast f32 -> bf16 (float4 vectorized) ----------------
__global__ void cast_f32_bf16(const float* __restrict__ in,
                              __hip_bfloat16* __restrict__ out, int n4) {
  int i = blockIdx.x * blockDim.x + threadIdx.x;
  if (i >= n4) return;
  float4 v = reinterpret_cast<const float4*>(in)[i];
  union { __hip_bfloat16 h[4]; ushort4 u; } cv;
  cv.h[0] = __float2bfloat16(v.x);
  cv.h[1] = __float2bfloat16(v.y);
  cv.h[2] = __float2bfloat16(v.z);
  cv.h[3] = __float2bfloat16(v.w);
  reinterpret_cast<ushort4*>(out)[i] = cv.u;
}

// ---------------- RoPE cos/sin table: [T][64] float2 ----------------
__global__ void rope_tab_kernel(float* __restrict__ tab) {
  int idx = blockIdx.x * blockDim.x + threadIdx.x;
  if (idx >= SEQT * 64) return;
  int j = idx & 63, t = idx >> 6;
  float inv = expf(-9.210340371976184f * (float)j / 64.0f);  // 10000^(-j/64)
  float ang = (float)t * inv;
  tab[idx * 2] = cosf(ang);
  tab[idx * 2 + 1] = sinf(ang);
}

// ---------------- m97-style bf16 GEMM:  C[M,N] = A[M,K] * B[N,K]^T ----------------
template <typename CT>
__global__ __launch_bounds__(256) void gemm_bt(
    const __hip_bfloat16* __restrict__ A, const __hip_bfloat16* __restrict__ Bm,
    CT* __restrict__ C, int M, int N, int K) {
  __shared__ __hip_bfloat16 As[128 * 32];
  __shared__ __hip_bfloat16 Bs[128 * 32];
  const int tid = threadIdx.x;
  const int lane = tid & 63;
  const int wave = tid >> 6;
  const int wr = wave >> 1, wc = wave & 1;
  const int m0 = blockIdx.y * 128, n0 = blockIdx.x * 128;
  const int lr = lane & 15, lg = lane >> 4;

  const __hip_bfloat16* Ap = A + (size_t)(m0 + (tid >> 2)) * K + (tid & 3) * 8;
  const __hip_bfloat16* Bp = Bm + (size_t)(n0 + (tid >> 2)) * K + (tid & 3) * 8;
  __hip_bfloat16* Asd = As + tid * 8;
  __hip_bfloat16* Bsd = Bs + tid * 8;

  f32x4 acc[4][4] = {};

  for (int k0 = 0; k0 < K; k0 += 32) {
    GLOAD_LDS(Ap + k0, Asd);
    GLOAD_LDS(Ap + (size_t)64 * K + k0, Asd + 2048);
    GLOAD_LDS(Bp + k0, Bsd);
    GLOAD_LDS(Bp + (size_t)64 * K + k0, Bsd + 2048);
    __syncthreads();
    frag8 a[4], b[4];
#pragma unroll
    for (int mi = 0; mi < 4; ++mi)
      a[mi] = *reinterpret_cast<const frag8*>(&As[(wr * 64 + mi * 16 + lr) * 32 + lg * 8]);
#pragma unroll
    for (int nj = 0; nj < 4; ++nj)
      b[nj] = *reinterpret_cast<const frag8*>(&Bs[(wc * 64 + nj * 16 + lr) * 32 + lg * 8]);
#pragma unroll
    for (int mi = 0; mi < 4; ++mi)
#pragma unroll
      for (int nj = 0; nj < 4; ++nj)
        acc[mi][nj] = MFMA(a[mi], b[nj], acc[mi][nj]);
    __syncthreads();
  }

#pragma unroll
  for (int mi = 0; mi < 4; ++mi)
#pragma unroll
    for (int nj = 0; nj < 4; ++nj)
#pragma unroll
      for (int i = 0; i < 4; ++i) {
        int row = m0 + wr * 64 + mi * 16 + lg * 4 + i;
        int col = n0 + wc * 64 + nj * 16 + lr;
        float v = acc[mi][nj][i];
        if constexpr (std::is_same<CT, __hip_bfloat16>::value)
          C[(size_t)row * N + col] = __float2bfloat16(v);
        else
          C[(size_t)row * N + col] = v;
      }
}

// ---------------- RoPE on q,k; scatter to [B,H,T,D]; fold 1/sqrt(128) into q ----------------
__global__ void rope_qk(const __hip_bfloat16* __restrict__ qkv,
                        const float* __restrict__ tab,
                        __hip_bfloat16* __restrict__ q,
                        __hip_bfloat16* __restrict__ k) {
  int idx = blockIdx.x * blockDim.x + threadIdx.x;  // B*T*H*64
  if (idx >= BATCH * SEQT * NHEADS * 64) return;
  int j = idx & 63;
  int h = (idx >> 6) & 15;
  int t = (idx >> 10) & 2047;
  int b = idx >> 21;
  float c = tab[(t * 64 + j) * 2];
  float s = tab[(t * 64 + j) * 2 + 1];
  size_t qi = (size_t)(b * SEQT + t) * (3 * DIMC) + h * HDIM + j;
  float q1 = __bfloat162float(qkv[qi]);
  float q2 = __bfloat162float(qkv[qi + 64]);
  float k1 = __bfloat162float(qkv[qi + DIMC]);
  float k2 = __bfloat162float(qkv[qi + DIMC + 64]);
  const float sc = 0.08838834764831845f;  // 1/sqrt(128)
  size_t oi = ((size_t)(b * NHEADS + h) * SEQT + t) * HDIM + j;
  q[oi] = __float2bfloat16((q1 * c - q2 * s) * sc);
  q[oi + 64] = __float2bfloat16((q1 * s + q2 * c) * sc);
  k[oi] = __float2bfloat16(k1 * c - k2 * s);
  k[oi + 64] = __float2bfloat16(k1 * s + k2 * c);
}

// ---------------- V transpose: qkv v-part -> vt[B,H,D,T] ----------------
__global__ __launch_bounds__(256) void transpose_v(
    const __hip_bfloat16* __restrict__ qkv, __hip_bfloat16* __restrict__ vt) {
  __shared__ __hip_bfloat16 tile[32][33];
  int t0 = blockIdx.x * 32;
  int d0 = blockIdx.y * 32;
  int bh = blockIdx.z;
  int b = bh >> 4, h = bh & 15;
  int x = threadIdx.x & 31, y = threadIdx.x >> 5;  // y: 0..7
#pragma unroll
  for (int r = 0; r < 4; ++r) {
    int tr = r * 8 + y;
    tile[tr][x] = qkv[(size_t)(b * SEQT + t0 + tr) * (3 * DIMC) + 2 * DIMC + h * HDIM + d0 + x];
  }
  __syncthreads();
#pragma unroll
  for (int r = 0; r < 4; ++r) {
    int dr = r * 8 + y;
    vt[((size_t)bh * HDIM + d0 + dr) * SEQT + t0 + x] = tile[x][dr];
  }
}

// ---------------- flash attention: 1 wave per 32 q-rows, KB=32 ----------------
// R4: no __syncthreads (1 wave/block -> barrier was a forced vmcnt(0) drain each
// iteration); K/V double-buffered in named A/B register sets (cross-iteration
// prefetch); s_setprio around MFMA clusters (T5, +4-7% on this exact structure);
// heavy q-tiles dispatched first (qt descending, bh fastest -> per-XCD KV ~2MB in L2).
__global__ __launch_bounds__(64) void flash_attn(
    const __hip_bfloat16* __restrict__ q, const __hip_bfloat16* __restrict__ k,
    const __hip_bfloat16* __restrict__ vt, __hip_bfloat16* __restrict__ ctx) {
  const int qt = 63 - (blockIdx.x >> 5);  // heavy tiles first
  const int bh = blockIdx.x & 31;         // bh fastest -> spreads across XCDs
  const int lane = threadIdx.x;
  const int lr = lane & 15, lg = lane >> 4;
  const size_t base = (size_t)bh * SEQT * HDIM;

  __shared__ __hip_bfloat16 P[32 * 40];  // stride 40 elems (80B = 5*16B)

  frag8 aq[2][4];
#pragma unroll
  for (int rt = 0; rt < 2; ++rt)
#pragma unroll
    for (int dc = 0; dc < 4; ++dc)
      aq[rt][dc] = *reinterpret_cast<const frag8*>(
          &q[base + (size_t)(qt * 32 + rt * 16 + lr) * HDIM + dc * 32 + lg * 8]);

  f32x4 o[2][8] = {};
  float mrun[2][4], lrun[2][4];
#pragma unroll
  for (int rt = 0; rt < 2; ++rt)
#pragma unroll
    for (int i = 0; i < 4; ++i) { mrun[rt][i] = -INFINITY; lrun[rt][i] = 0.f; }

  auto loadK = [&](frag8 (&bk)[2][4], int kb) {
#pragma unroll
    for (int st = 0; st < 2; ++st)
#pragma unroll
      for (int dc = 0; dc < 4; ++dc)
        bk[st][dc] = *reinterpret_cast<const frag8*>(
            &k[base + (size_t)(kb * 32 + st * 16 + lr) * HDIM + dc * 32 + lg * 8]);
  };
  auto loadV = [&](frag8 (&bv)[8], int kb) {
#pragma unroll
    for (int dt = 0; dt < 8; ++dt)
      bv[dt] = *reinterpret_cast<const frag8*>(
          &vt[base + (size_t)(dt * 16 + lr) * SEQT + kb * 32 + lg * 8]);
  };

  auto compute = [&](frag8 (&bk)[2][4], frag8 (&bv)[8], int kb) {
    f32x4 s[2][2] = {};
    __builtin_amdgcn_s_setprio(1);
#pragma unroll
    for (int rt = 0; rt < 2; ++rt)
#pragma unroll
      for (int st = 0; st < 2; ++st)
#pragma unroll
        for (int dc = 0; dc < 4; ++dc)
          s[rt][st] = MFMA(aq[rt][dc], bk[st][dc], s[rt][st]);
    __builtin_amdgcn_s_setprio(0);

    if (kb == qt) {  // diagonal block: causal mask (local coords)
#pragma unroll
      for (int rt = 0; rt < 2; ++rt)
#pragma unroll
        for (int st = 0; st < 2; ++st)
#pragma unroll
          for (int i = 0; i < 4; ++i)
            if (st * 16 + lr > rt * 16 + lg * 4 + i) s[rt][st][i] = -INFINITY;
    }

#pragma unroll
    for (int rt = 0; rt < 2; ++rt)
#pragma unroll
      for (int i = 0; i < 4; ++i) {
        float pm = fmaxf(s[rt][0][i], s[rt][1][i]);
        pm = fmaxf(pm, __shfl_xor(pm, 1, 16));
        pm = fmaxf(pm, __shfl_xor(pm, 2, 16));
        pm = fmaxf(pm, __shfl_xor(pm, 4, 16));
        pm = fmaxf(pm, __shfl_xor(pm, 8, 16));
        float mn = fmaxf(mrun[rt][i], pm);
        float sf = __expf(mrun[rt][i] - mn);
        mrun[rt][i] = mn;
        float p0 = __expf(s[rt][0][i] - mn);
        float p1 = __expf(s[rt][1][i] - mn);
        float rs = p0 + p1;
        rs += __shfl_xor(rs, 1, 16);
        rs += __shfl_xor(rs, 2, 16);
        rs += __shfl_xor(rs, 4, 16);
        rs += __shfl_xor(rs, 8, 16);
        lrun[rt][i] = lrun[rt][i] * sf + rs;
#pragma unroll
        for (int dt = 0; dt < 8; ++dt) o[rt][dt][i] *= sf;
        P[(rt * 16 + lg * 4 + i) * 40 + lr] = __float2bfloat16(p0);
        P[(rt * 16 + lg * 4 + i) * 40 + 16 + lr] = __float2bfloat16(p1);
      }
    // no barrier: single wave, in-wave LDS ordering via lgkmcnt (compiler)

    frag8 pa[2];
#pragma unroll
    for (int rt = 0; rt < 2; ++rt)
      pa[rt] = *reinterpret_cast<const frag8*>(&P[(rt * 16 + lr) * 40 + lg * 8]);

    __builtin_amdgcn_s_setprio(1);
#pragma unroll
    for (int rt = 0; rt < 2; ++rt)
#pragma unroll
      for (int dt = 0; dt < 8; ++dt)
        o[rt][dt] = MFMA(pa[rt], bv[dt], o[rt][dt]);
    __builtin_amdgcn_s_setprio(0);
  };

  frag8 kA[2][4], vA[8], kB[2][4], vB[8];
  loadK(kA, 0);
  loadV(vA, 0);
  int kb = 0;
  while (true) {
    if (kb + 1 <= qt) { loadK(kB, kb + 1); loadV(vB, kb + 1); }
    compute(kA, vA, kb);
    if (++kb > qt) break;
    if (kb + 1 <= qt) { loadK(kA, kb + 1); loadV(vA, kb + 1); }
    compute(kB, vB, kb);
    if (++kb > qt) break;
  }

  const int b = bh >> 4, h = bh & 15;
#pragma unroll
  for (int rt = 0; rt < 2; ++rt)
#pragma unroll
    for (int i = 0; i < 4; ++i) {
      float inv = 1.0f / lrun[rt][i];
      int row = qt * 32 + rt * 16 + lg * 4 + i;
#pragma unroll
      for (int dt = 0; dt < 8; ++dt)
        ctx[(size_t)(b * SEQT + row) * DIMC + h * HDIM + dt * 16 + lr] =
            __float2bfloat16(o[rt][dt][i] * inv);
    }
}

// ---------------- launch ----------------
extern "C" void kernel_launch(void* const* d_in, const int* in_sizes, int n_in,
                              void* d_out, int out_size, void* d_ws, size_t ws_size,
                              hipStream_t stream) {
  const float* x = (const float*)d_in[0];
  const float* w_qkv = (const float*)d_in[1];
  const float* w_out = (const float*)d_in[2];
  float* out = (float*)d_out;
  char* ws = (char*)d_ws;

  const size_t WS_NEEDED = 110100480;
  if (ws_size < WS_NEEDED) {  // defensive: visible wrong-output instead of an OOB fault
    zero_out_kernel<<<(out_size + 255) / 256, 256, 0, stream>>>(out, out_size);
    return;
  }

  __hip_bfloat16* qkvb  = (__hip_bfloat16*)(ws);
  __hip_bfloat16* ctx   = (__hip_bfloat16*)(ws);
  __hip_bfloat16* qbuf  = (__hip_bfloat16*)(ws + 50331648);
  __hip_bfloat16* kbuf  = (__hip_bfloat16*)(ws + 67108864);
  __hip_bfloat16* vtb   = (__hip_bfloat16*)(ws + 83886080);
  __hip_bfloat16* xb    = (__hip_bfloat16*)(ws + 50331648);
  __hip_bfloat16* wqkvb = (__hip_bfloat16*)(ws + 67108864);
  __hip_bfloat16* woutb = (__hip_bfloat16*)(ws + 100663296);
  float* tab            = (float*)(ws + 109051904);

  cast_f32_bf16<<<8192, 256, 0, stream>>>(x, xb, 2097152);
  cast_f32_bf16<<<12288, 256, 0, stream>>>(w_qkv, wqkvb, 3145728);
  cast_f32_bf16<<<4096, 256, 0, stream>>>(w_out, woutb, 1048576);
  rope_tab_kernel<<<512, 256, 0, stream>>>(tab);
  gemm_bt<__hip_bfloat16><<<dim3(48, 32), 256, 0, stream>>>(xb, wqkvb, qkvb, 4096, 6144, 2048);
  rope_qk<<<16384, 256, 0, stream>>>(qkvb, tab, qbuf, kbuf);
  transpose_v<<<dim3(64, 4, 32), 256, 0, stream>>>(qkvb, vtb);
  flash_attn<<<2048, 64, 0, stream>>>(qbuf, kbuf, vtb, ctx);
  gemm_bt<float><<<dim3(16, 32), 256, 0, stream>>>(ctx, woutb, out, 4096, 2048, 2048);
}

// Round 8
// 464.671 us; speedup vs baseline: 1.2586x; 1.1399x over previous
//
#include <hip/hip_runtime.h>
#include <hip/hip_bf16.h>
#include <cmath>
#include <type_traits>

#define DIMC 2048
#define NHEADS 16
#define HDIM 128
#define SEQT 2048
#define BATCH 2

#define EXP2(x) __builtin_amdgcn_exp2f(x)  // v_exp_f32 = 2^x; glibc owns the __exp2f name

using frag8 = __attribute__((ext_vector_type(8))) short;   // 8 bf16 = 4 VGPRs
using f32x4 = __attribute__((ext_vector_type(4))) float;

#define MFMA(a, b, c) __builtin_amdgcn_mfma_f32_16x16x32_bf16((a), (b), (c), 0, 0, 0)

#define GLOAD_LDS(g, l)                                              \
  __builtin_amdgcn_global_load_lds(                                  \
      (const __attribute__((address_space(1))) void*)(g),            \
      (__attribute__((address_space(3))) void*)(l), 16, 0, 0)

// ---------------- fallback: zero the output (ws too small -> visible failure, not a fault) ----
__global__ void zero_out_kernel(float* __restrict__ out, int n) {
  int i = blockIdx.x * blockDim.x + threadIdx.x;
  if (i < n) out[i] = 0.0f;
}

// ---------------- cast f32 -> bf16 (float4 vectorized) ----------------
__global__ void cast_f32_bf16(const float* __restrict__ in,
                              __hip_bfloat16* __restrict__ out, int n4) {
  int i = blockIdx.x * blockDim.x + threadIdx.x;
  if (i >= n4) return;
  float4 v = reinterpret_cast<const float4*>(in)[i];
  union { __hip_bfloat16 h[4]; ushort4 u; } cv;
  cv.h[0] = __float2bfloat16(v.x);
  cv.h[1] = __float2bfloat16(v.y);
  cv.h[2] = __float2bfloat16(v.z);
  cv.h[3] = __float2bfloat16(v.w);
  reinterpret_cast<ushort4*>(out)[i] = cv.u;
}

// ---------------- RoPE cos/sin table: [T][64] float2 ----------------
__global__ void rope_tab_kernel(float* __restrict__ tab) {
  int idx = blockIdx.x * blockDim.x + threadIdx.x;
  if (idx >= SEQT * 64) return;
  int j = idx & 63, t = idx >> 6;
  float inv = expf(-9.210340371976184f * (float)j / 64.0f);  // 10000^(-j/64)
  float ang = (float)t * inv;
  tab[idx * 2] = cosf(ang);
  tab[idx * 2 + 1] = sinf(ang);
}

// ---------------- m97-style bf16 GEMM:  C[M,N] = A[M,K] * B[N,K]^T ----------------
template <typename CT>
__global__ __launch_bounds__(256) void gemm_bt(
    const __hip_bfloat16* __restrict__ A, const __hip_bfloat16* __restrict__ Bm,
    CT* __restrict__ C, int M, int N, int K) {
  __shared__ __hip_bfloat16 As[128 * 32];
  __shared__ __hip_bfloat16 Bs[128 * 32];
  const int tid = threadIdx.x;
  const int lane = tid & 63;
  const int wave = tid >> 6;
  const int wr = wave >> 1, wc = wave & 1;
  const int m0 = blockIdx.y * 128, n0 = blockIdx.x * 128;
  const int lr = lane & 15, lg = lane >> 4;

  const __hip_bfloat16* Ap = A + (size_t)(m0 + (tid >> 2)) * K + (tid & 3) * 8;
  const __hip_bfloat16* Bp = Bm + (size_t)(n0 + (tid >> 2)) * K + (tid & 3) * 8;
  __hip_bfloat16* Asd = As + tid * 8;
  __hip_bfloat16* Bsd = Bs + tid * 8;

  f32x4 acc[4][4] = {};

  for (int k0 = 0; k0 < K; k0 += 32) {
    GLOAD_LDS(Ap + k0, Asd);
    GLOAD_LDS(Ap + (size_t)64 * K + k0, Asd + 2048);
    GLOAD_LDS(Bp + k0, Bsd);
    GLOAD_LDS(Bp + (size_t)64 * K + k0, Bsd + 2048);
    __syncthreads();
    frag8 a[4], b[4];
#pragma unroll
    for (int mi = 0; mi < 4; ++mi)
      a[mi] = *reinterpret_cast<const frag8*>(&As[(wr * 64 + mi * 16 + lr) * 32 + lg * 8]);
#pragma unroll
    for (int nj = 0; nj < 4; ++nj)
      b[nj] = *reinterpret_cast<const frag8*>(&Bs[(wc * 64 + nj * 16 + lr) * 32 + lg * 8]);
#pragma unroll
    for (int mi = 0; mi < 4; ++mi)
#pragma unroll
      for (int nj = 0; nj < 4; ++nj)
        acc[mi][nj] = MFMA(a[mi], b[nj], acc[mi][nj]);
    __syncthreads();
  }

#pragma unroll
  for (int mi = 0; mi < 4; ++mi)
#pragma unroll
    for (int nj = 0; nj < 4; ++nj)
#pragma unroll
      for (int i = 0; i < 4; ++i) {
        int row = m0 + wr * 64 + mi * 16 + lg * 4 + i;
        int col = n0 + wc * 64 + nj * 16 + lr;
        float v = acc[mi][nj][i];
        if constexpr (std::is_same<CT, __hip_bfloat16>::value)
          C[(size_t)row * N + col] = __float2bfloat16(v);
        else
          C[(size_t)row * N + col] = v;
      }
}

// ---------------- RoPE on q,k; scatter to [B,H,T,D] ----------------
// q scale = 1/sqrt(128) * log2(e): attention logits are computed in base-2
// domain so flash_attn can use exp2 (v_exp_f32, 1 instr) instead of expf.
__global__ void rope_qk(const __hip_bfloat16* __restrict__ qkv,
                        const float* __restrict__ tab,
                        __hip_bfloat16* __restrict__ q,
                        __hip_bfloat16* __restrict__ k) {
  int idx = blockIdx.x * blockDim.x + threadIdx.x;  // B*T*H*64
  if (idx >= BATCH * SEQT * NHEADS * 64) return;
  int j = idx & 63;
  int h = (idx >> 6) & 15;
  int t = (idx >> 10) & 2047;
  int b = idx >> 21;
  float c = tab[(t * 64 + j) * 2];
  float s = tab[(t * 64 + j) * 2 + 1];
  size_t qi = (size_t)(b * SEQT + t) * (3 * DIMC) + h * HDIM + j;
  float q1 = __bfloat162float(qkv[qi]);
  float q2 = __bfloat162float(qkv[qi + 64]);
  float k1 = __bfloat162float(qkv[qi + DIMC]);
  float k2 = __bfloat162float(qkv[qi + DIMC + 64]);
  const float sc = 0.12751744945137108f;  // (1/sqrt(128)) * log2(e)
  size_t oi = ((size_t)(b * NHEADS + h) * SEQT + t) * HDIM + j;
  q[oi] = __float2bfloat16((q1 * c - q2 * s) * sc);
  q[oi + 64] = __float2bfloat16((q1 * s + q2 * c) * sc);
  k[oi] = __float2bfloat16(k1 * c - k2 * s);
  k[oi + 64] = __float2bfloat16(k1 * s + k2 * c);
}

// ---------------- V transpose: qkv v-part -> vt[B,H,D,T] ----------------
__global__ __launch_bounds__(256) void transpose_v(
    const __hip_bfloat16* __restrict__ qkv, __hip_bfloat16* __restrict__ vt) {
  __shared__ __hip_bfloat16 tile[32][33];
  int t0 = blockIdx.x * 32;
  int d0 = blockIdx.y * 32;
  int bh = blockIdx.z;
  int b = bh >> 4, h = bh & 15;
  int x = threadIdx.x & 31, y = threadIdx.x >> 5;  // y: 0..7
#pragma unroll
  for (int r = 0; r < 4; ++r) {
    int tr = r * 8 + y;
    tile[tr][x] = qkv[(size_t)(b * SEQT + t0 + tr) * (3 * DIMC) + 2 * DIMC + h * HDIM + d0 + x];
  }
  __syncthreads();
#pragma unroll
  for (int r = 0; r < 4; ++r) {
    int dr = r * 8 + y;
    vt[((size_t)bh * HDIM + d0 + dr) * SEQT + t0 + x] = tile[x][dr];
  }
}

// ---------------- flash attention: 1 wave per 32 q-rows, KB=32 ----------------
// R6b: (a) deferred l-sum: lrun is a per-lane partial (sum over this lane's
// k-columns), reduced ONCE at block end -> removes 32 shfl/iter.
// (b) defer-max (T13, THR = 8*log2e): per-lane threshold test + __all; common
// case skips max-reduce shuffles, o-rescale, and mrun update entirely.
// (c) base-2 logits (scale folded in rope_qk) -> EXP2 = v_exp_f32, 1 instr.
__global__ __launch_bounds__(64) void flash_attn(
    const __hip_bfloat16* __restrict__ q, const __hip_bfloat16* __restrict__ k,
    const __hip_bfloat16* __restrict__ vt, __hip_bfloat16* __restrict__ ctx) {
  const int qt = 63 - (blockIdx.x >> 5);  // heavy tiles first
  const int bh = blockIdx.x & 31;         // bh fastest -> spreads across XCDs
  const int lane = threadIdx.x;
  const int lr = lane & 15, lg = lane >> 4;
  const size_t base = (size_t)bh * SEQT * HDIM;
  const float THR = 11.54f;  // 8 * log2(e): P bounded by e^8

  __shared__ __hip_bfloat16 P[32 * 40];  // stride 40 elems (80B = 5*16B)

  frag8 aq[2][4];
#pragma unroll
  for (int rt = 0; rt < 2; ++rt)
#pragma unroll
    for (int dc = 0; dc < 4; ++dc)
      aq[rt][dc] = *reinterpret_cast<const frag8*>(
          &q[base + (size_t)(qt * 32 + rt * 16 + lr) * HDIM + dc * 32 + lg * 8]);

  f32x4 o[2][8] = {};
  float mrun[2][4], lrun[2][4];
#pragma unroll
  for (int rt = 0; rt < 2; ++rt)
#pragma unroll
    for (int i = 0; i < 4; ++i) { mrun[rt][i] = -INFINITY; lrun[rt][i] = 0.f; }

  auto loadK = [&](frag8 (&bk)[2][4], int kb) {
#pragma unroll
    for (int st = 0; st < 2; ++st)
#pragma unroll
      for (int dc = 0; dc < 4; ++dc)
        bk[st][dc] = *reinterpret_cast<const frag8*>(
            &k[base + (size_t)(kb * 32 + st * 16 + lr) * HDIM + dc * 32 + lg * 8]);
  };
  auto loadV = [&](frag8 (&bv)[8], int kb) {
#pragma unroll
    for (int dt = 0; dt < 8; ++dt)
      bv[dt] = *reinterpret_cast<const frag8*>(
          &vt[base + (size_t)(dt * 16 + lr) * SEQT + kb * 32 + lg * 8]);
  };

  auto compute = [&](frag8 (&bk)[2][4], frag8 (&bv)[8], int kb) {
    f32x4 s[2][2] = {};
    __builtin_amdgcn_s_setprio(1);
#pragma unroll
    for (int rt = 0; rt < 2; ++rt)
#pragma unroll
      for (int st = 0; st < 2; ++st)
#pragma unroll
        for (int dc = 0; dc < 4; ++dc)
          s[rt][st] = MFMA(aq[rt][dc], bk[st][dc], s[rt][st]);
    __builtin_amdgcn_s_setprio(0);

    if (kb == qt) {  // diagonal block: causal mask (local coords)
#pragma unroll
      for (int rt = 0; rt < 2; ++rt)
#pragma unroll
        for (int st = 0; st < 2; ++st)
#pragma unroll
          for (int i = 0; i < 4; ++i)
            if (st * 16 + lr > rt * 16 + lg * 4 + i) s[rt][st][i] = -INFINITY;
    }

    // defer-max test: per-lane, no cross-lane reduce needed.
    // __all(s - mrun <= THR) => true max <= mrun + THR for every pair.
    float excess = -INFINITY;
#pragma unroll
    for (int rt = 0; rt < 2; ++rt)
#pragma unroll
      for (int i = 0; i < 4; ++i)
        excess = fmaxf(excess,
                       fmaxf(s[rt][0][i], s[rt][1][i]) - mrun[rt][i]);

    if (__all(excess <= THR)) {
      // fast path: keep old max; no rescale, no shuffles.
#pragma unroll
      for (int rt = 0; rt < 2; ++rt)
#pragma unroll
        for (int i = 0; i < 4; ++i) {
          float p0 = EXP2(s[rt][0][i] - mrun[rt][i]);
          float p1 = EXP2(s[rt][1][i] - mrun[rt][i]);
          lrun[rt][i] += p0 + p1;  // per-lane partial
          P[(rt * 16 + lg * 4 + i) * 40 + lr] = __float2bfloat16(p0);
          P[(rt * 16 + lg * 4 + i) * 40 + 16 + lr] = __float2bfloat16(p1);
        }
    } else {
      // slow path: full online-softmax max update + rescale.
#pragma unroll
      for (int rt = 0; rt < 2; ++rt)
#pragma unroll
        for (int i = 0; i < 4; ++i) {
          float pm = fmaxf(s[rt][0][i], s[rt][1][i]);
          pm = fmaxf(pm, __shfl_xor(pm, 1, 16));
          pm = fmaxf(pm, __shfl_xor(pm, 2, 16));
          pm = fmaxf(pm, __shfl_xor(pm, 4, 16));
          pm = fmaxf(pm, __shfl_xor(pm, 8, 16));
          float mn = fmaxf(mrun[rt][i], pm);
          float sf = EXP2(mrun[rt][i] - mn);
          mrun[rt][i] = mn;
          float p0 = EXP2(s[rt][0][i] - mn);
          float p1 = EXP2(s[rt][1][i] - mn);
          lrun[rt][i] = lrun[rt][i] * sf + (p0 + p1);
#pragma unroll
          for (int dt = 0; dt < 8; ++dt) o[rt][dt][i] *= sf;
          P[(rt * 16 + lg * 4 + i) * 40 + lr] = __float2bfloat16(p0);
          P[(rt * 16 + lg * 4 + i) * 40 + 16 + lr] = __float2bfloat16(p1);
        }
    }
    // no barrier: single wave, in-wave LDS ordering via lgkmcnt (compiler)

    frag8 pa[2];
#pragma unroll
    for (int rt = 0; rt < 2; ++rt)
      pa[rt] = *reinterpret_cast<const frag8*>(&P[(rt * 16 + lr) * 40 + lg * 8]);

    __builtin_amdgcn_s_setprio(1);
#pragma unroll
    for (int rt = 0; rt < 2; ++rt)
#pragma unroll
      for (int dt = 0; dt < 8; ++dt)
        o[rt][dt] = MFMA(pa[rt], bv[dt], o[rt][dt]);
    __builtin_amdgcn_s_setprio(0);
  };

  frag8 kA[2][4], vA[8], kB[2][4], vB[8];
  loadK(kA, 0);
  loadV(vA, 0);
  int kb = 0;
  while (true) {
    if (kb + 1 <= qt) { loadK(kB, kb + 1); loadV(vB, kb + 1); }
    compute(kA, vA, kb);
    if (++kb > qt) break;
    if (kb + 1 <= qt) { loadK(kA, kb + 1); loadV(vA, kb + 1); }
    compute(kB, vB, kb);
    if (++kb > qt) break;
  }

  const int b = bh >> 4, h = bh & 15;
#pragma unroll
  for (int rt = 0; rt < 2; ++rt)
#pragma unroll
    for (int i = 0; i < 4; ++i) {
      // final cross-lane reduce of the deferred per-lane partials (once).
      float ls = lrun[rt][i];
      ls += __shfl_xor(ls, 1, 16);
      ls += __shfl_xor(ls, 2, 16);
      ls += __shfl_xor(ls, 4, 16);
      ls += __shfl_xor(ls, 8, 16);
      float inv = 1.0f / ls;
      int row = qt * 32 + rt * 16 + lg * 4 + i;
#pragma unroll
      for (int dt = 0; dt < 8; ++dt)
        ctx[(size_t)(b * SEQT + row) * DIMC + h * HDIM + dt * 16 + lr] =
            __float2bfloat16(o[rt][dt][i] * inv);
    }
}

// ---------------- launch ----------------
extern "C" void kernel_launch(void* const* d_in, const int* in_sizes, int n_in,
                              void* d_out, int out_size, void* d_ws, size_t ws_size,
                              hipStream_t stream) {
  const float* x = (const float*)d_in[0];
  const float* w_qkv = (const float*)d_in[1];
  const float* w_out = (const float*)d_in[2];
  float* out = (float*)d_out;
  char* ws = (char*)d_ws;

  const size_t WS_NEEDED = 110100480;
  if (ws_size < WS_NEEDED) {  // defensive: visible wrong-output instead of an OOB fault
    zero_out_kernel<<<(out_size + 255) / 256, 256, 0, stream>>>(out, out_size);
    return;
  }

  __hip_bfloat16* qkvb  = (__hip_bfloat16*)(ws);
  __hip_bfloat16* ctx   = (__hip_bfloat16*)(ws);
  __hip_bfloat16* qbuf  = (__hip_bfloat16*)(ws + 50331648);
  __hip_bfloat16* kbuf  = (__hip_bfloat16*)(ws + 67108864);
  __hip_bfloat16* vtb   = (__hip_bfloat16*)(ws + 83886080);
  __hip_bfloat16* xb    = (__hip_bfloat16*)(ws + 50331648);
  __hip_bfloat16* wqkvb = (__hip_bfloat16*)(ws + 67108864);
  __hip_bfloat16* woutb = (__hip_bfloat16*)(ws + 100663296);
  float* tab            = (float*)(ws + 109051904);

  cast_f32_bf16<<<8192, 256, 0, stream>>>(x, xb, 2097152);
  cast_f32_bf16<<<12288, 256, 0, stream>>>(w_qkv, wqkvb, 3145728);
  cast_f32_bf16<<<4096, 256, 0, stream>>>(w_out, woutb, 1048576);
  rope_tab_kernel<<<512, 256, 0, stream>>>(tab);
  gemm_bt<__hip_bfloat16><<<dim3(48, 32), 256, 0, stream>>>(xb, wqkvb, qkvb, 4096, 6144, 2048);
  rope_qk<<<16384, 256, 0, stream>>>(qkvb, tab, qbuf, kbuf);
  transpose_v<<<dim3(64, 4, 32), 256, 0, stream>>>(qkvb, vtb);
  flash_attn<<<2048, 64, 0, stream>>>(qbuf, kbuf, vtb, ctx);
  gemm_bt<float><<<dim3(16, 32), 256, 0, stream>>>(ctx, woutb, out, 4096, 2048, 2048);
}